// Round 3
// baseline (1203.718 us; speedup 1.0000x reference)
//
#include <hip/hip_runtime.h>
#include <math.h>

#define B_    2
#define S_    2048
#define HID_  1024
#define H_    16
#define D_    64
#define KEEP_ 204
#define QT_   8

typedef __attribute__((ext_vector_type(8))) short short8;
typedef __attribute__((ext_vector_type(4))) float f32x4;

// order-preserving fp32 -> uint32 mapping (larger float <=> larger uint)
__device__ __forceinline__ unsigned f2u_ord(float x) {
    unsigned b = __float_as_uint(x);
    return (b & 0x80000000u) ? ~b : (b | 0x80000000u);
}
__device__ __forceinline__ float u2f_ord(unsigned u) {
    unsigned b = (u & 0x80000000u) ? (u ^ 0x80000000u) : ~u;
    return __uint_as_float(b);
}
__device__ __forceinline__ float wave_sum(float x) {
    #pragma unroll
    for (int off = 32; off > 0; off >>= 1) x += __shfl_xor(x, off);
    return x;
}
__device__ __forceinline__ unsigned wave_max_u(unsigned x) {
    #pragma unroll
    for (int off = 32; off > 0; off >>= 1) {
        unsigned t = __shfl_xor(x, off);
        x = (t > x) ? t : x;
    }
    return x;
}
__device__ __forceinline__ unsigned short bf16rn(float x) {
    unsigned u = __float_as_uint(x);
    return (unsigned short)((u + 0x7fffu + ((u >> 16) & 1u)) >> 16);
}
__device__ __forceinline__ float bfhi2f(unsigned short h) {
    return __uint_as_float((unsigned)h << 16);
}

// ---------------- x (flat fp32) -> bf16 hi/lo ----------------
__global__ __launch_bounds__(256) void conv_x_k(
    const float* __restrict__ X,
    unsigned short* __restrict__ Xh, unsigned short* __restrict__ Xl)
{
    const int i = blockIdx.x * 256 + threadIdx.x;
    const float4 v = ((const float4*)X)[i];
    ushort4 h, l;
    h.x = bf16rn(v.x); l.x = bf16rn(v.x - bfhi2f(h.x));
    h.y = bf16rn(v.y); l.y = bf16rn(v.y - bfhi2f(h.y));
    h.z = bf16rn(v.z); l.z = bf16rn(v.z - bfhi2f(h.z));
    h.w = bf16rn(v.w); l.w = bf16rn(v.w - bfhi2f(h.w));
    ((ushort4*)Xh)[i] = h;
    ((ushort4*)Xl)[i] = l;
}

// ---------------- W [K][N] fp32 -> Wt [N][K] bf16 hi/lo (transpose) ----------------
__global__ __launch_bounds__(256) void conv_wT_k(
    const float* __restrict__ W,
    unsigned short* __restrict__ Wth, unsigned short* __restrict__ Wtl)
{
    __shared__ float t[64][65];
    const int k0 = blockIdx.y * 64, n0 = blockIdx.x * 64;
    const int r = threadIdx.x >> 4, c4 = (threadIdx.x & 15) * 4;
    #pragma unroll
    for (int i = 0; i < 4; i++) {
        const float4 v = *(const float4*)&W[(size_t)(k0 + r + 16 * i) * HID_ + n0 + c4];
        t[r + 16 * i][c4 + 0] = v.x;
        t[r + 16 * i][c4 + 1] = v.y;
        t[r + 16 * i][c4 + 2] = v.z;
        t[r + 16 * i][c4 + 3] = v.w;
    }
    __syncthreads();
    #pragma unroll
    for (int i = 0; i < 4; i++) {
        const int n = r + 16 * i;
        float a0 = t[c4 + 0][n], a1 = t[c4 + 1][n], a2 = t[c4 + 2][n], a3 = t[c4 + 3][n];
        ushort4 h, l;
        h.x = bf16rn(a0); l.x = bf16rn(a0 - bfhi2f(h.x));
        h.y = bf16rn(a1); l.y = bf16rn(a1 - bfhi2f(h.y));
        h.z = bf16rn(a2); l.z = bf16rn(a2 - bfhi2f(h.z));
        h.w = bf16rn(a3); l.w = bf16rn(a3 - bfhi2f(h.w));
        const size_t idx = (size_t)(n0 + n) * HID_ + k0 + c4;
        *(ushort4*)&Wth[idx] = h;
        *(ushort4*)&Wtl[idx] = l;
    }
}

// ---------------- fused Q/K/V split-bf16 MFMA GEMM ----------------
// grid.z: 0=Q (hi/lo, x1/8), 1=K (hi/lo), 2=V -> TRANSPOSED bf16 Vt[bh][d][s]
// lo*lo term dropped: contributes ~2^-16 relative (sigma ~1e-7 here).
__global__ __launch_bounds__(256) void gemm_qkv_k(
    const unsigned short* __restrict__ Ah, const unsigned short* __restrict__ Al,
    const unsigned short* __restrict__ Bhq, const unsigned short* __restrict__ Blq,
    const unsigned short* __restrict__ Bhk, const unsigned short* __restrict__ Blk,
    const unsigned short* __restrict__ Bhv, const unsigned short* __restrict__ Blv,
    const float* __restrict__ bq, const float* __restrict__ bk, const float* __restrict__ bv,
    unsigned short* __restrict__ Qh, unsigned short* __restrict__ Ql,
    unsigned short* __restrict__ Kh, unsigned short* __restrict__ Kl,
    unsigned short* __restrict__ Vt)
{
    const int z = blockIdx.z;
    const unsigned short* Bth = (z == 0) ? Bhq : (z == 1) ? Bhk : Bhv;
    const unsigned short* Btl = (z == 0) ? Blq : (z == 1) ? Blk : Blv;
    const float* bias = (z == 0) ? bq : (z == 1) ? bk : bv;

    const int lane = threadIdx.x & 63;
    const int wv = threadIdx.x >> 6;
    const int m0 = blockIdx.y * 64 + (wv & 1) * 32;
    const int n0 = blockIdx.x * 128 + (wv >> 1) * 64;
    const int rl = lane & 15, quad = lane >> 4;

    f32x4 acc[2][4];
    #pragma unroll
    for (int mt = 0; mt < 2; mt++)
        #pragma unroll
        for (int nt = 0; nt < 4; nt++)
            acc[mt][nt] = (f32x4){0.f, 0.f, 0.f, 0.f};

    const size_t arow0 = (size_t)(m0 + rl) * HID_ + quad * 8;
    const size_t brow0 = (size_t)(n0 + rl) * HID_ + quad * 8;

    #pragma unroll 2
    for (int k0 = 0; k0 < HID_; k0 += 32) {
        short8 a_h[2], a_l[2], b_h[4], b_l[4];
        #pragma unroll
        for (int mt = 0; mt < 2; mt++) {
            a_h[mt] = *(const short8*)&Ah[arow0 + (size_t)mt * 16 * HID_ + k0];
            a_l[mt] = *(const short8*)&Al[arow0 + (size_t)mt * 16 * HID_ + k0];
        }
        #pragma unroll
        for (int nt = 0; nt < 4; nt++) {
            b_h[nt] = *(const short8*)&Bth[brow0 + (size_t)nt * 16 * HID_ + k0];
            b_l[nt] = *(const short8*)&Btl[brow0 + (size_t)nt * 16 * HID_ + k0];
        }
        #pragma unroll
        for (int mt = 0; mt < 2; mt++)
            #pragma unroll
            for (int nt = 0; nt < 4; nt++) {
                acc[mt][nt] = __builtin_amdgcn_mfma_f32_16x16x32_bf16(a_l[mt], b_h[nt], acc[mt][nt], 0, 0, 0);
                acc[mt][nt] = __builtin_amdgcn_mfma_f32_16x16x32_bf16(a_h[mt], b_l[nt], acc[mt][nt], 0, 0, 0);
                acc[mt][nt] = __builtin_amdgcn_mfma_f32_16x16x32_bf16(a_h[mt], b_h[nt], acc[mt][nt], 0, 0, 0);
            }
    }

    const float scale = (z == 0) ? 0.125f : 1.0f;
    #pragma unroll
    for (int nt = 0; nt < 4; nt++) {
        const int cn = n0 + nt * 16 + rl;
        const float bs = bias[cn];
        const int h = cn >> 6, d = cn & 63;
        #pragma unroll
        for (int mt = 0; mt < 2; mt++) {
            #pragma unroll
            for (int reg = 0; reg < 4; reg++) {
                const int rm = m0 + mt * 16 + quad * 4 + reg;
                const int b = rm >> 11, s = rm & (S_ - 1);
                const float v = acc[mt][nt][reg] + bs;
                if (z == 2) {
                    // transposed: Vt[bh][d][s]
                    Vt[((size_t)(b * H_ + h) * D_ + d) * S_ + s] = bf16rn(v);
                } else {
                    const size_t idx = ((size_t)(b * H_ + h) * S_ + s) * D_ + d;
                    const float vs = v * scale;
                    const unsigned short hb = bf16rn(vs);
                    const unsigned short lb = bf16rn(vs - bfhi2f(hb));
                    if (z == 0) { Qh[idx] = hb; Ql[idx] = lb; }
                    else        { Kh[idx] = hb; Kl[idx] = lb; }
                }
            }
        }
    }
}

// ---------------- O-GEMM: out = AO @ Wo + bo (fp32 out) ----------------
__global__ __launch_bounds__(256) void gemm_o_k(
    const unsigned short* __restrict__ Ah, const unsigned short* __restrict__ Al,
    const unsigned short* __restrict__ Bth, const unsigned short* __restrict__ Btl,
    const float* __restrict__ bias, float* __restrict__ Y)
{
    const int lane = threadIdx.x & 63;
    const int wv = threadIdx.x >> 6;
    const int m0 = blockIdx.y * 64 + (wv & 1) * 32;
    const int n0 = blockIdx.x * 128 + (wv >> 1) * 64;
    const int rl = lane & 15, quad = lane >> 4;

    f32x4 acc[2][4];
    #pragma unroll
    for (int mt = 0; mt < 2; mt++)
        #pragma unroll
        for (int nt = 0; nt < 4; nt++)
            acc[mt][nt] = (f32x4){0.f, 0.f, 0.f, 0.f};

    const size_t arow0 = (size_t)(m0 + rl) * HID_ + quad * 8;
    const size_t brow0 = (size_t)(n0 + rl) * HID_ + quad * 8;

    #pragma unroll 2
    for (int k0 = 0; k0 < HID_; k0 += 32) {
        short8 a_h[2], a_l[2], b_h[4], b_l[4];
        #pragma unroll
        for (int mt = 0; mt < 2; mt++) {
            a_h[mt] = *(const short8*)&Ah[arow0 + (size_t)mt * 16 * HID_ + k0];
            a_l[mt] = *(const short8*)&Al[arow0 + (size_t)mt * 16 * HID_ + k0];
        }
        #pragma unroll
        for (int nt = 0; nt < 4; nt++) {
            b_h[nt] = *(const short8*)&Bth[brow0 + (size_t)nt * 16 * HID_ + k0];
            b_l[nt] = *(const short8*)&Btl[brow0 + (size_t)nt * 16 * HID_ + k0];
        }
        #pragma unroll
        for (int mt = 0; mt < 2; mt++)
            #pragma unroll
            for (int nt = 0; nt < 4; nt++) {
                acc[mt][nt] = __builtin_amdgcn_mfma_f32_16x16x32_bf16(a_l[mt], b_h[nt], acc[mt][nt], 0, 0, 0);
                acc[mt][nt] = __builtin_amdgcn_mfma_f32_16x16x32_bf16(a_h[mt], b_l[nt], acc[mt][nt], 0, 0, 0);
                acc[mt][nt] = __builtin_amdgcn_mfma_f32_16x16x32_bf16(a_h[mt], b_h[nt], acc[mt][nt], 0, 0, 0);
            }
    }

    #pragma unroll
    for (int nt = 0; nt < 4; nt++) {
        const int cn = n0 + nt * 16 + rl;
        const float bs = bias[cn];
        #pragma unroll
        for (int mt = 0; mt < 2; mt++)
            #pragma unroll
            for (int reg = 0; reg < 4; reg++) {
                const int rm = m0 + mt * 16 + quad * 4 + reg;
                Y[(size_t)rm * HID_ + cn] = acc[mt][nt][reg] + bs;
            }
    }
}

// ---------------- fused MFMA scores + exact top-204 + DENSE-MFMA sparse-softmax PV ----
// 512 threads = 8 waves. Ballot-counted radix-2 bit-descent with exact early exit.
// Weights stored in LDS as k-tiles [ch][row][32] (tile = 512 B): PV's 32 distinct
// lane addresses are 32 consecutive 16B chunks -> conflict-free ds_read_b128
// (old [row][WPAD] layout was ~7-way conflicted: 12.85M SQ_LDS_BANK_CONFLICT).
// PV is depth-2 software-pipelined with dual accumulator chains.
__global__ __launch_bounds__(512, 6) void attn_topk_k(
    const unsigned short* __restrict__ Qhi, const unsigned short* __restrict__ Qlo,
    const unsigned short* __restrict__ Khi, const unsigned short* __restrict__ Klo,
    const unsigned short* __restrict__ Vt,
    unsigned short* __restrict__ AOh, unsigned short* __restrict__ AOl)
{
    const int tid = threadIdx.x;
    const int wv = tid >> 6;                  // 0..7 — this wave's query row
    const int lane = tid & 63;
    // XCD-locality remap: 4 bh per XCD -> K+Vt working set < one L2
    const int xcd = blockIdx.x & 7;
    const int w = blockIdx.x >> 3;
    const int bh = xcd * 4 + (w >> 8);
    const int q0 = (w & 255) * QT_;
    const int b = bh >> 4, h = bh & (H_ - 1);

    __shared__ __align__(16) unsigned char smem[32768 + 4096 + 64];
    float (*sc)[1024] = (float (*)[1024])smem;           // scores view (32 KB)
    unsigned short* w16 = (unsigned short*)smem;          // weights view [64][8][32]
    float* partial = (float*)(smem + 32768);              // [2][8][64]
    float* denomL  = (float*)(smem + 32768 + 4096);       // [8]

    const int mrow = lane & 15, quad = lane >> 4;

    // ---- A-fragments: Q hi/lo, rows duplicated (m&7) ----
    const size_t qrow = ((size_t)bh * S_ + q0 + (mrow & 7)) * D_;
    const short8 Ah0 = *(const short8*)&Qhi[qrow + quad * 8];
    const short8 Ah1 = *(const short8*)&Qhi[qrow + 32 + quad * 8];
    const short8 Al0 = *(const short8*)&Qlo[qrow + quad * 8];
    const short8 Al1 = *(const short8*)&Qlo[qrow + 32 + quad * 8];

    const size_t kbase = (size_t)bh * S_ * D_;
    unsigned uu[32];   // slot cc <-> j = cc*64 + lane

    #pragma unroll
    for (int r = 0; r < 2; r++) {
        size_t koff = kbase + (size_t)(r * 1024 + wv * 128 + mrow) * D_ + quad * 8;
        #pragma unroll 1
        for (int tl = 0; tl < 8; tl++) {
            const short8 Bh0 = *(const short8*)&Khi[koff];
            const short8 Bh1 = *(const short8*)&Khi[koff + 32];
            const short8 Bl0 = *(const short8*)&Klo[koff];
            const short8 Bl1 = *(const short8*)&Klo[koff + 32];
            f32x4 acc0 = {0.f, 0.f, 0.f, 0.f};
            f32x4 acc1 = {0.f, 0.f, 0.f, 0.f};
            __builtin_amdgcn_s_setprio(1);
            acc0 = __builtin_amdgcn_mfma_f32_16x16x32_bf16(Al0, Bl0, acc0, 0, 0, 0);
            acc1 = __builtin_amdgcn_mfma_f32_16x16x32_bf16(Al1, Bl1, acc1, 0, 0, 0);
            acc0 = __builtin_amdgcn_mfma_f32_16x16x32_bf16(Al0, Bh0, acc0, 0, 0, 0);
            acc1 = __builtin_amdgcn_mfma_f32_16x16x32_bf16(Al1, Bh1, acc1, 0, 0, 0);
            acc0 = __builtin_amdgcn_mfma_f32_16x16x32_bf16(Ah0, Bl0, acc0, 0, 0, 0);
            acc1 = __builtin_amdgcn_mfma_f32_16x16x32_bf16(Ah1, Bl1, acc1, 0, 0, 0);
            acc0 = __builtin_amdgcn_mfma_f32_16x16x32_bf16(Ah0, Bh0, acc0, 0, 0, 0);
            acc1 = __builtin_amdgcn_mfma_f32_16x16x32_bf16(Ah1, Bh1, acc1, 0, 0, 0);
            __builtin_amdgcn_s_setprio(0);
            if (lane < 32) {   // C: row=quad*4+reg (0..7 in lanes 0..31), col=lane&15
                const int colb = wv * 128 + tl * 16 + (lane & 15);
                #pragma unroll
                for (int reg = 0; reg < 4; reg++)
                    sc[quad * 4 + reg][colb] = acc0[reg] + acc1[reg];
            }
            koff += (size_t)16 * D_;
        }
        __syncthreads();   // round-r strips written
        #pragma unroll
        for (int c = 0; c < 16; c++)
            uu[r * 16 + c] = f2u_ord(sc[wv][c * 64 + lane]);
        __syncthreads();   // reads done; next round may overwrite
    }

    // row max (ordered uints); sparse row includes zeros -> clamp to 0
    unsigned um = 0u;
    #pragma unroll
    for (int c = 0; c < 32; c++) { const unsigned t = uu[c]; um = (t > um) ? t : um; }
    um = wave_max_u(um);
    um = __builtin_amdgcn_readfirstlane(um);   // keep threshold chain scalar
    const float m = fmaxf(u2f_ord(um), 0.0f);
    const float em = __expf(-m);

    // ---- exact threshold: ballot-counted radix-2 bit-descent ----
    unsigned p = 0;
    int cge = S_;          // count of values >= p (p=0 -> all)
    #pragma unroll 1
    for (int bit = 31; bit >= 0; bit--) {
        if (cge == KEEP_) break;
        const unsigned trial = p | (1u << bit);
        if (trial > um) continue;
        int c = 0;
        #pragma unroll
        for (int i = 0; i < 32; i++)
            c += (int)__popcll(__ballot(uu[i] >= trial));
        if (c >= KEEP_) { p = trial; cge = c; }
    }
    const unsigned T = p;

    // ---- tie selection ----
    unsigned tieMask = 0;
    if (cge == KEEP_) {
        // exact hit: all ties at T are selected
        #pragma unroll
        for (int c = 0; c < 32; c++)
            if (uu[c] == T) tieMask |= 1u << c;
    } else {
        // rare path: take first `rem' ties in ascending j
        int cgt = 0;
        #pragma unroll
        for (int i = 0; i < 32; i++)
            cgt += (int)__popcll(__ballot(uu[i] > T));
        int need = KEEP_ - cgt;                // #ties to take (>=1)
        const unsigned long long below = (1ULL << lane) - 1ULL;
        #pragma unroll
        for (int c = 0; c < 32; c++) {
            const bool eq = (uu[c] == T);
            const unsigned long long mg = __ballot(eq);
            if (eq && (int)__popcll(mg & below) < need) tieMask |= 1u << c;
            const int cnt = (int)__popcll(mg);
            need -= (cnt < need) ? cnt : need;
        }
    }

    // ---- dense bf16 weight row + denominator from stored weights ----
    // layout: k = c*64 + lane -> tile ch = k>>5 (=2c + (lane>>5)), kk = k&31;
    // w16[ch*256 + wv*32 + kk]
    float esum = 0.f;
    {
        const int chb = (lane >> 5);
        const int kk = lane & 31;
        #pragma unroll
        for (int c = 0; c < 32; c++) {
            const unsigned u = uu[c];
            const bool sel = (u > T) || ((tieMask >> c) & 1u);
            const float wgt = sel ? __expf(u2f_ord(u) - m) : em;
            const unsigned short wb = bf16rn(wgt);
            esum += bfhi2f(wb);
            w16[(((c << 1) | chb) << 8) + (wv << 5) + kk] = wb;
        }
    }
    const float denom = wave_sum(esum);
    if (lane == 0) denomL[wv] = denom;
    __syncthreads();   // weights + denoms visible to all waves

    // ---- PV via MFMA: wave = (n-tile = wv&3, K-half = wv>>2) ----
    // depth-2 pipelined, dual accumulator chains, conflict-free LDS reads
    {
        const int ntile = wv & 3;
        const int khalf = wv >> 2;
        const unsigned short* VtB =
            Vt + ((size_t)bh * D_ + ntile * 16 + mrow) * S_ + khalf * 1024 + quad * 8;
        const unsigned short* wbase =
            w16 + ((khalf * 32) << 8) + ((mrow & 7) << 5) + quad * 8;
        f32x4 pacc0 = {0.f, 0.f, 0.f, 0.f};
        f32x4 pacc1 = {0.f, 0.f, 0.f, 0.f};
        short8 aw0 = *(const short8*)&wbase[0];
        short8 bv0 = *(const short8*)&VtB[0];
        __builtin_amdgcn_s_setprio(1);
        #pragma unroll 2
        for (int ch = 0; ch < 31; ch++) {
            const short8 awn = *(const short8*)&wbase[(ch + 1) << 8];
            const short8 bvn = *(const short8*)&VtB[(ch + 1) * 32];
            if (ch & 1)
                pacc1 = __builtin_amdgcn_mfma_f32_16x16x32_bf16(aw0, bv0, pacc1, 0, 0, 0);
            else
                pacc0 = __builtin_amdgcn_mfma_f32_16x16x32_bf16(aw0, bv0, pacc0, 0, 0, 0);
            aw0 = awn; bv0 = bvn;
        }
        pacc1 = __builtin_amdgcn_mfma_f32_16x16x32_bf16(aw0, bv0, pacc1, 0, 0, 0);
        __builtin_amdgcn_s_setprio(0);
        const f32x4 pacc = pacc0 + pacc1;
        if (quad < 2) {
            #pragma unroll
            for (int reg = 0; reg < 4; reg++)
                partial[(khalf * 8 + quad * 4 + reg) * 64 + ntile * 16 + mrow] = pacc[reg];
        }
    }
    __syncthreads();   // partials visible

    // ---- reduce K-halves, normalize, write AO (bf16 hi/lo) ----
    {
        const int q = tid >> 6;       // 0..7
        const int d = tid & 63;
        const float o = (partial[q * 64 + d] + partial[(8 + q) * 64 + d]) / denomL[q];
        const unsigned short hb = bf16rn(o);
        const unsigned short lb = bf16rn(o - bfhi2f(hb));
        const size_t oidx = ((size_t)(b * S_ + q0 + q)) * HID_ + h * D_ + d;
        AOh[oidx] = hb;
        AOl[oidx] = lb;
    }
}

extern "C" void kernel_launch(void* const* d_in, const int* in_sizes, int n_in,
                              void* d_out, int out_size, void* d_ws, size_t ws_size,
                              hipStream_t stream) {
    const float* x  = (const float*)d_in[0];
    const float* Wq = (const float*)d_in[1];
    const float* bq = (const float*)d_in[2];
    const float* Wk = (const float*)d_in[3];
    const float* bk = (const float*)d_in[4];
    const float* Wv = (const float*)d_in[5];
    const float* bv = (const float*)d_in[6];
    const float* Wo = (const float*)d_in[7];
    const float* bo = (const float*)d_in[8];
    float* out = (float*)d_out;

    const size_t NQ = (size_t)B_ * H_ * S_ * D_;   // 4,194,304 elements
    const size_t NW = (size_t)HID_ * HID_;         // 1,048,576 elements
    unsigned short* p = (unsigned short*)d_ws;
    unsigned short* xh   = p; p += NQ;   // also AOh (x dead after QKV GEMM)
    unsigned short* xl   = p; p += NQ;   // also AOl
    unsigned short* Wt_h[4];
    unsigned short* Wt_l[4];
    for (int i = 0; i < 4; i++) { Wt_h[i] = p; p += NW; Wt_l[i] = p; p += NW; }
    unsigned short* Qhi = p; p += NQ;
    unsigned short* Qlo = p; p += NQ;
    unsigned short* Khi = p; p += NQ;
    unsigned short* Klo = p; p += NQ;
    unsigned short* Vt  = p; p += NQ;
    unsigned short* AOh = xh;
    unsigned short* AOl = xl;

    dim3 blk(256);
    conv_x_k<<<dim3(NQ / 1024), blk, 0, stream>>>(x, xh, xl);
    conv_wT_k<<<dim3(16, 16), blk, 0, stream>>>(Wq, Wt_h[0], Wt_l[0]);
    conv_wT_k<<<dim3(16, 16), blk, 0, stream>>>(Wk, Wt_h[1], Wt_l[1]);
    conv_wT_k<<<dim3(16, 16), blk, 0, stream>>>(Wv, Wt_h[2], Wt_l[2]);
    conv_wT_k<<<dim3(16, 16), blk, 0, stream>>>(Wo, Wt_h[3], Wt_l[3]);

    dim3 gqkv(HID_ / 128, (B_ * S_) / 64, 3);
    gemm_qkv_k<<<gqkv, blk, 0, stream>>>(xh, xl,
        Wt_h[0], Wt_l[0], Wt_h[1], Wt_l[1], Wt_h[2], Wt_l[2],
        bq, bk, bv, Qhi, Qlo, Khi, Klo, Vt);
    attn_topk_k<<<dim3(B_ * H_ * (S_ / QT_)), dim3(512), 0, stream>>>(
        Qhi, Qlo, Khi, Klo, Vt, AOh, AOl);
    dim3 go(HID_ / 128, (B_ * S_) / 64);
    gemm_o_k<<<go, blk, 0, stream>>>(AOh, AOl, Wt_h[3], Wt_l[3], bo, out);
}

// Round 4
// 1076.513 us; speedup vs baseline: 1.1182x; 1.1182x over previous
//
#include <hip/hip_runtime.h>
#include <math.h>

#define B_    2
#define S_    2048
#define HID_  1024
#define H_    16
#define D_    64
#define KEEP_ 204
#define QT_   16

typedef __attribute__((ext_vector_type(8))) short short8;
typedef __attribute__((ext_vector_type(4))) float f32x4;

// order-preserving fp32 -> uint32 mapping (larger float <=> larger uint)
__device__ __forceinline__ unsigned f2u_ord(float x) {
    unsigned b = __float_as_uint(x);
    return (b & 0x80000000u) ? ~b : (b | 0x80000000u);
}
__device__ __forceinline__ float u2f_ord(unsigned u) {
    unsigned b = (u & 0x80000000u) ? (u ^ 0x80000000u) : ~u;
    return __uint_as_float(b);
}
__device__ __forceinline__ float wave_sum(float x) {
    #pragma unroll
    for (int off = 32; off > 0; off >>= 1) x += __shfl_xor(x, off);
    return x;
}
__device__ __forceinline__ unsigned wave_max_u(unsigned x) {
    #pragma unroll
    for (int off = 32; off > 0; off >>= 1) {
        unsigned t = __shfl_xor(x, off);
        x = (t > x) ? t : x;
    }
    return x;
}
__device__ __forceinline__ unsigned short bf16rn(float x) {
    unsigned u = __float_as_uint(x);
    return (unsigned short)((u + 0x7fffu + ((u >> 16) & 1u)) >> 16);
}
__device__ __forceinline__ float bfhi2f(unsigned short h) {
    return __uint_as_float((unsigned)h << 16);
}

// ---------------- x (flat fp32) -> bf16 hi/lo ----------------
__global__ __launch_bounds__(256) void conv_x_k(
    const float* __restrict__ X,
    unsigned short* __restrict__ Xh, unsigned short* __restrict__ Xl)
{
    const int i = blockIdx.x * 256 + threadIdx.x;
    const float4 v = ((const float4*)X)[i];
    ushort4 h, l;
    h.x = bf16rn(v.x); l.x = bf16rn(v.x - bfhi2f(h.x));
    h.y = bf16rn(v.y); l.y = bf16rn(v.y - bfhi2f(h.y));
    h.z = bf16rn(v.z); l.z = bf16rn(v.z - bfhi2f(h.z));
    h.w = bf16rn(v.w); l.w = bf16rn(v.w - bfhi2f(h.w));
    ((ushort4*)Xh)[i] = h;
    ((ushort4*)Xl)[i] = l;
}

// ---------------- W [K][N] fp32 -> Wt [N][K] bf16 hi/lo (transpose) ----------------
__global__ __launch_bounds__(256) void conv_wT_k(
    const float* __restrict__ W,
    unsigned short* __restrict__ Wth, unsigned short* __restrict__ Wtl)
{
    __shared__ float t[64][65];
    const int k0 = blockIdx.y * 64, n0 = blockIdx.x * 64;
    const int r = threadIdx.x >> 4, c4 = (threadIdx.x & 15) * 4;
    #pragma unroll
    for (int i = 0; i < 4; i++) {
        const float4 v = *(const float4*)&W[(size_t)(k0 + r + 16 * i) * HID_ + n0 + c4];
        t[r + 16 * i][c4 + 0] = v.x;
        t[r + 16 * i][c4 + 1] = v.y;
        t[r + 16 * i][c4 + 2] = v.z;
        t[r + 16 * i][c4 + 3] = v.w;
    }
    __syncthreads();
    #pragma unroll
    for (int i = 0; i < 4; i++) {
        const int n = r + 16 * i;
        float a0 = t[c4 + 0][n], a1 = t[c4 + 1][n], a2 = t[c4 + 2][n], a3 = t[c4 + 3][n];
        ushort4 h, l;
        h.x = bf16rn(a0); l.x = bf16rn(a0 - bfhi2f(h.x));
        h.y = bf16rn(a1); l.y = bf16rn(a1 - bfhi2f(h.y));
        h.z = bf16rn(a2); l.z = bf16rn(a2 - bfhi2f(h.z));
        h.w = bf16rn(a3); l.w = bf16rn(a3 - bfhi2f(h.w));
        const size_t idx = (size_t)(n0 + n) * HID_ + k0 + c4;
        *(ushort4*)&Wth[idx] = h;
        *(ushort4*)&Wtl[idx] = l;
    }
}

// ---------------- fused Q/K/V split-bf16 MFMA GEMM ----------------
// grid.z: 0=Q (hi/lo, x1/8), 1=K (hi/lo), 2=V -> TRANSPOSED bf16 Vt[bh][d][s]
// lo*lo term dropped: contributes ~2^-16 relative.
__global__ __launch_bounds__(256) void gemm_qkv_k(
    const unsigned short* __restrict__ Ah, const unsigned short* __restrict__ Al,
    const unsigned short* __restrict__ Bhq, const unsigned short* __restrict__ Blq,
    const unsigned short* __restrict__ Bhk, const unsigned short* __restrict__ Blk,
    const unsigned short* __restrict__ Bhv, const unsigned short* __restrict__ Blv,
    const float* __restrict__ bq, const float* __restrict__ bk, const float* __restrict__ bv,
    unsigned short* __restrict__ Qh, unsigned short* __restrict__ Ql,
    unsigned short* __restrict__ Kh, unsigned short* __restrict__ Kl,
    unsigned short* __restrict__ Vt)
{
    const int z = blockIdx.z;
    const unsigned short* Bth = (z == 0) ? Bhq : (z == 1) ? Bhk : Bhv;
    const unsigned short* Btl = (z == 0) ? Blq : (z == 1) ? Blk : Blv;
    const float* bias = (z == 0) ? bq : (z == 1) ? bk : bv;

    const int lane = threadIdx.x & 63;
    const int wv = threadIdx.x >> 6;
    const int m0 = blockIdx.y * 64 + (wv & 1) * 32;
    const int n0 = blockIdx.x * 128 + (wv >> 1) * 64;
    const int rl = lane & 15, quad = lane >> 4;

    f32x4 acc[2][4];
    #pragma unroll
    for (int mt = 0; mt < 2; mt++)
        #pragma unroll
        for (int nt = 0; nt < 4; nt++)
            acc[mt][nt] = (f32x4){0.f, 0.f, 0.f, 0.f};

    const size_t arow0 = (size_t)(m0 + rl) * HID_ + quad * 8;
    const size_t brow0 = (size_t)(n0 + rl) * HID_ + quad * 8;

    #pragma unroll 2
    for (int k0 = 0; k0 < HID_; k0 += 32) {
        short8 a_h[2], a_l[2], b_h[4], b_l[4];
        #pragma unroll
        for (int mt = 0; mt < 2; mt++) {
            a_h[mt] = *(const short8*)&Ah[arow0 + (size_t)mt * 16 * HID_ + k0];
            a_l[mt] = *(const short8*)&Al[arow0 + (size_t)mt * 16 * HID_ + k0];
        }
        #pragma unroll
        for (int nt = 0; nt < 4; nt++) {
            b_h[nt] = *(const short8*)&Bth[brow0 + (size_t)nt * 16 * HID_ + k0];
            b_l[nt] = *(const short8*)&Btl[brow0 + (size_t)nt * 16 * HID_ + k0];
        }
        #pragma unroll
        for (int mt = 0; mt < 2; mt++)
            #pragma unroll
            for (int nt = 0; nt < 4; nt++) {
                acc[mt][nt] = __builtin_amdgcn_mfma_f32_16x16x32_bf16(a_l[mt], b_h[nt], acc[mt][nt], 0, 0, 0);
                acc[mt][nt] = __builtin_amdgcn_mfma_f32_16x16x32_bf16(a_h[mt], b_l[nt], acc[mt][nt], 0, 0, 0);
                acc[mt][nt] = __builtin_amdgcn_mfma_f32_16x16x32_bf16(a_h[mt], b_h[nt], acc[mt][nt], 0, 0, 0);
            }
    }

    const float scale = (z == 0) ? 0.125f : 1.0f;
    #pragma unroll
    for (int nt = 0; nt < 4; nt++) {
        const int cn = n0 + nt * 16 + rl;
        const float bs = bias[cn];
        const int h = cn >> 6, d = cn & 63;
        #pragma unroll
        for (int mt = 0; mt < 2; mt++) {
            #pragma unroll
            for (int reg = 0; reg < 4; reg++) {
                const int rm = m0 + mt * 16 + quad * 4 + reg;
                const int b = rm >> 11, s = rm & (S_ - 1);
                const float v = acc[mt][nt][reg] + bs;
                if (z == 2) {
                    // transposed: Vt[bh][d][s]
                    Vt[((size_t)(b * H_ + h) * D_ + d) * S_ + s] = bf16rn(v);
                } else {
                    const size_t idx = ((size_t)(b * H_ + h) * S_ + s) * D_ + d;
                    const float vs = v * scale;
                    const unsigned short hb = bf16rn(vs);
                    const unsigned short lb = bf16rn(vs - bfhi2f(hb));
                    if (z == 0) { Qh[idx] = hb; Ql[idx] = lb; }
                    else        { Kh[idx] = hb; Kl[idx] = lb; }
                }
            }
        }
    }
}

// ---------------- O-GEMM: out = AO @ Wo + bo (fp32 out) ----------------
__global__ __launch_bounds__(256) void gemm_o_k(
    const unsigned short* __restrict__ Ah, const unsigned short* __restrict__ Al,
    const unsigned short* __restrict__ Bth, const unsigned short* __restrict__ Btl,
    const float* __restrict__ bias, float* __restrict__ Y)
{
    const int lane = threadIdx.x & 63;
    const int wv = threadIdx.x >> 6;
    const int m0 = blockIdx.y * 64 + (wv & 1) * 32;
    const int n0 = blockIdx.x * 128 + (wv >> 1) * 64;
    const int rl = lane & 15, quad = lane >> 4;

    f32x4 acc[2][4];
    #pragma unroll
    for (int mt = 0; mt < 2; mt++)
        #pragma unroll
        for (int nt = 0; nt < 4; nt++)
            acc[mt][nt] = (f32x4){0.f, 0.f, 0.f, 0.f};

    const size_t arow0 = (size_t)(m0 + rl) * HID_ + quad * 8;
    const size_t brow0 = (size_t)(n0 + rl) * HID_ + quad * 8;

    #pragma unroll 2
    for (int k0 = 0; k0 < HID_; k0 += 32) {
        short8 a_h[2], a_l[2], b_h[4], b_l[4];
        #pragma unroll
        for (int mt = 0; mt < 2; mt++) {
            a_h[mt] = *(const short8*)&Ah[arow0 + (size_t)mt * 16 * HID_ + k0];
            a_l[mt] = *(const short8*)&Al[arow0 + (size_t)mt * 16 * HID_ + k0];
        }
        #pragma unroll
        for (int nt = 0; nt < 4; nt++) {
            b_h[nt] = *(const short8*)&Bth[brow0 + (size_t)nt * 16 * HID_ + k0];
            b_l[nt] = *(const short8*)&Btl[brow0 + (size_t)nt * 16 * HID_ + k0];
        }
        #pragma unroll
        for (int mt = 0; mt < 2; mt++)
            #pragma unroll
            for (int nt = 0; nt < 4; nt++) {
                acc[mt][nt] = __builtin_amdgcn_mfma_f32_16x16x32_bf16(a_l[mt], b_h[nt], acc[mt][nt], 0, 0, 0);
                acc[mt][nt] = __builtin_amdgcn_mfma_f32_16x16x32_bf16(a_h[mt], b_l[nt], acc[mt][nt], 0, 0, 0);
                acc[mt][nt] = __builtin_amdgcn_mfma_f32_16x16x32_bf16(a_h[mt], b_h[nt], acc[mt][nt], 0, 0, 0);
            }
    }

    #pragma unroll
    for (int nt = 0; nt < 4; nt++) {
        const int cn = n0 + nt * 16 + rl;
        const float bs = bias[cn];
        #pragma unroll
        for (int mt = 0; mt < 2; mt++)
            #pragma unroll
            for (int reg = 0; reg < 4; reg++) {
                const int rm = m0 + mt * 16 + quad * 4 + reg;
                Y[(size_t)rm * HID_ + cn] = acc[mt][nt][reg] + bs;
            }
    }
}

// ---------------- fused MFMA scores + exact top-204 + DENSE-MFMA sparse-softmax PV ----
// RESTRUCTURED: 1024 threads = 16 waves, QT=16 queries per block, 16 DISTINCT
// M-rows per MFMA (no more mrow&7 duplication -> score & PV MFMA count halved,
// K/Vt L2 traffic per query halved, block count halved: 4096 blocks).
// Each wave owns one query row (wv=0..15) for top-k; per score round, wave wv
// computes a 16q x 64key strip. Weights stored as k-tiles [ch][q16][kk32];
// PV: wave=(ntile=wv&3, kq=wv>>2), 16 MFMAs, partials reduced via LDS atomicAdd.
__global__ __launch_bounds__(1024, 8) void attn_topk_k(
    const unsigned short* __restrict__ Qhi, const unsigned short* __restrict__ Qlo,
    const unsigned short* __restrict__ Khi, const unsigned short* __restrict__ Klo,
    const unsigned short* __restrict__ Vt,
    unsigned short* __restrict__ AOh, unsigned short* __restrict__ AOl)
{
    const int tid = threadIdx.x;
    const int wv = tid >> 6;                  // 0..15 — this wave's query row
    const int lane = tid & 63;
    // XCD-locality remap: 4 bh per XCD -> K+Vt working set < one L2
    const int xcd = blockIdx.x & 7;
    const int w = blockIdx.x >> 3;
    const int bh = xcd * 4 + (w >> 7);
    const int q0 = (w & 127) * QT_;
    const int b = bh >> 4, h = bh & (H_ - 1);

    __shared__ __align__(16) unsigned char smem[65536 + 4096 + 64];
    float (*sc)[1024] = (float (*)[1024])smem;        // scores view [16][1024] (64 KB)
    unsigned short* w16 = (unsigned short*)smem;      // weights view [64][16][32] (64 KB)
    float* partial = (float*)(smem + 65536);          // [16][64]
    float* denomL  = (float*)(smem + 65536 + 4096);   // [16]

    const int mrow = lane & 15, quad = lane >> 4;

    // ---- A-fragments: Q hi/lo, 16 distinct query rows ----
    const size_t qrow = ((size_t)bh * S_ + q0 + mrow) * D_;
    const short8 Ah0 = *(const short8*)&Qhi[qrow + quad * 8];
    const short8 Ah1 = *(const short8*)&Qhi[qrow + 32 + quad * 8];
    const short8 Al0 = *(const short8*)&Qlo[qrow + quad * 8];
    const short8 Al1 = *(const short8*)&Qlo[qrow + 32 + quad * 8];

    const size_t kbase = (size_t)bh * S_ * D_;
    unsigned uu[32];   // slot (r*16+c) <-> key j = r*1024 + c*64 + lane

    #pragma unroll
    for (int r = 0; r < 2; r++) {
        size_t koff = kbase + (size_t)(r * 1024 + wv * 64 + mrow) * D_ + quad * 8;
        #pragma unroll 1
        for (int tl = 0; tl < 4; tl++) {
            const short8 Bh0 = *(const short8*)&Khi[koff];
            const short8 Bh1 = *(const short8*)&Khi[koff + 32];
            const short8 Bl0 = *(const short8*)&Klo[koff];
            const short8 Bl1 = *(const short8*)&Klo[koff + 32];
            f32x4 acc0 = {0.f, 0.f, 0.f, 0.f};
            f32x4 acc1 = {0.f, 0.f, 0.f, 0.f};
            __builtin_amdgcn_s_setprio(1);
            acc0 = __builtin_amdgcn_mfma_f32_16x16x32_bf16(Al0, Bl0, acc0, 0, 0, 0);
            acc1 = __builtin_amdgcn_mfma_f32_16x16x32_bf16(Al1, Bl1, acc1, 0, 0, 0);
            acc0 = __builtin_amdgcn_mfma_f32_16x16x32_bf16(Al0, Bh0, acc0, 0, 0, 0);
            acc1 = __builtin_amdgcn_mfma_f32_16x16x32_bf16(Al1, Bh1, acc1, 0, 0, 0);
            acc0 = __builtin_amdgcn_mfma_f32_16x16x32_bf16(Ah0, Bl0, acc0, 0, 0, 0);
            acc1 = __builtin_amdgcn_mfma_f32_16x16x32_bf16(Ah1, Bl1, acc1, 0, 0, 0);
            acc0 = __builtin_amdgcn_mfma_f32_16x16x32_bf16(Ah0, Bh0, acc0, 0, 0, 0);
            acc1 = __builtin_amdgcn_mfma_f32_16x16x32_bf16(Ah1, Bh1, acc1, 0, 0, 0);
            __builtin_amdgcn_s_setprio(0);
            // C: row = quad*4+reg (0..15, = query), col = lane&15 (key in tile)
            const int colb = wv * 64 + tl * 16 + mrow;
            #pragma unroll
            for (int reg = 0; reg < 4; reg++)
                sc[quad * 4 + reg][colb] = acc0[reg] + acc1[reg];
            koff += (size_t)16 * D_;
        }
        __syncthreads();   // round-r strips written
        #pragma unroll
        for (int c = 0; c < 16; c++)
            uu[r * 16 + c] = f2u_ord(sc[wv][c * 64 + lane]);
        __syncthreads();   // reads done; next round (or weights) may overwrite
    }

    // row max (ordered uints); sparse row includes zeros -> clamp to 0
    unsigned um = 0u;
    #pragma unroll
    for (int c = 0; c < 32; c++) { const unsigned t = uu[c]; um = (t > um) ? t : um; }
    um = wave_max_u(um);
    um = __builtin_amdgcn_readfirstlane(um);   // keep threshold chain scalar
    const float m = fmaxf(u2f_ord(um), 0.0f);
    const float em = __expf(-m);

    // ---- exact threshold: ballot-counted radix-2 bit-descent ----
    unsigned p = 0;
    int cge = S_;          // count of values >= p (p=0 -> all)
    #pragma unroll 1
    for (int bit = 31; bit >= 0; bit--) {
        if (cge == KEEP_) break;
        const unsigned trial = p | (1u << bit);
        if (trial > um) continue;
        int c = 0;
        #pragma unroll
        for (int i = 0; i < 32; i++)
            c += (int)__popcll(__ballot(uu[i] >= trial));
        if (c >= KEEP_) { p = trial; cge = c; }
    }
    const unsigned T = p;

    // ---- tie selection ----
    unsigned tieMask = 0;
    if (cge == KEEP_) {
        // exact hit: all ties at T are selected
        #pragma unroll
        for (int c = 0; c < 32; c++)
            if (uu[c] == T) tieMask |= 1u << c;
    } else {
        // rare path: take first `rem' ties in ascending j
        int cgt = 0;
        #pragma unroll
        for (int i = 0; i < 32; i++)
            cgt += (int)__popcll(__ballot(uu[i] > T));
        int need = KEEP_ - cgt;                // #ties to take (>=1)
        const unsigned long long below = (1ULL << lane) - 1ULL;
        #pragma unroll
        for (int c = 0; c < 32; c++) {
            const bool eq = (uu[c] == T);
            const unsigned long long mg = __ballot(eq);
            if (eq && (int)__popcll(mg & below) < need) tieMask |= 1u << c;
            const int cnt = (int)__popcll(mg);
            need -= (cnt < need) ? cnt : need;
        }
    }

    // ---- dense bf16 weight row + denominator from stored weights ----
    // key j = r*1024 + cc*64 + lane -> tile ch = j>>5 = r*32 + cc*2 + (lane>>5),
    // kk = j&31 = lane&31; layout w16[ch*512 + q*32 + kk] (tile = 16q x 32k)
    float esum = 0.f;
    {
        const int lh = lane >> 5;
        const int kk = lane & 31;
        #pragma unroll
        for (int c = 0; c < 32; c++) {
            const unsigned u = uu[c];
            const bool sel = (u > T) || ((tieMask >> c) & 1u);
            const float wgt = sel ? __expf(u2f_ord(u) - m) : em;
            const unsigned short wb = bf16rn(wgt);
            esum += bfhi2f(wb);
            const int ch = (c >> 4) * 32 + (c & 15) * 2 + lh;
            w16[ch * 512 + wv * 32 + kk] = wb;
        }
    }
    const float denom = wave_sum(esum);
    if (lane == 0) denomL[wv] = denom;
    partial[tid] = 0.f;    // zero PV accumulator (exactly 1024 floats)
    __syncthreads();       // weights + denoms + zeroed partial visible

    // ---- PV via MFMA: wave = (ntile = wv&3 -> d-cols, kq = wv>>2 -> key quarter)
    {
        const int ntile = wv & 3;
        const int kq = wv >> 2;
        const unsigned short* VtB =
            Vt + ((size_t)bh * D_ + ntile * 16 + mrow) * S_ + kq * 512 + quad * 8;
        const unsigned short* wbase = w16 + kq * 16 * 512 + mrow * 32 + quad * 8;
        f32x4 pacc0 = {0.f, 0.f, 0.f, 0.f};
        f32x4 pacc1 = {0.f, 0.f, 0.f, 0.f};
        #pragma unroll 2
        for (int ch = 0; ch < 16; ch += 2) {
            const short8 aw0 = *(const short8*)&wbase[ch * 512];
            const short8 bv0 = *(const short8*)&VtB[ch * 32];
            const short8 aw1 = *(const short8*)&wbase[(ch + 1) * 512];
            const short8 bv1 = *(const short8*)&VtB[(ch + 1) * 32];
            pacc0 = __builtin_amdgcn_mfma_f32_16x16x32_bf16(aw0, bv0, pacc0, 0, 0, 0);
            pacc1 = __builtin_amdgcn_mfma_f32_16x16x32_bf16(aw1, bv1, pacc1, 0, 0, 0);
        }
        const f32x4 pacc = pacc0 + pacc1;
        // C: row = quad*4+reg (query), col = lane&15 (d within ntile)
        #pragma unroll
        for (int reg = 0; reg < 4; reg++)
            atomicAdd(&partial[(quad * 4 + reg) * 64 + ntile * 16 + mrow], pacc[reg]);
    }
    __syncthreads();   // partials reduced

    // ---- normalize, write AO (bf16 hi/lo) ----
    {
        const int q = tid >> 6;       // 0..15
        const int d = tid & 63;
        const float o = partial[q * 64 + d] / denomL[q];
        const unsigned short hb = bf16rn(o);
        const unsigned short lb = bf16rn(o - bfhi2f(hb));
        const size_t oidx = ((size_t)(b * S_ + q0 + q)) * HID_ + h * D_ + d;
        AOh[oidx] = hb;
        AOl[oidx] = lb;
    }
}

extern "C" void kernel_launch(void* const* d_in, const int* in_sizes, int n_in,
                              void* d_out, int out_size, void* d_ws, size_t ws_size,
                              hipStream_t stream) {
    const float* x  = (const float*)d_in[0];
    const float* Wq = (const float*)d_in[1];
    const float* bq = (const float*)d_in[2];
    const float* Wk = (const float*)d_in[3];
    const float* bk = (const float*)d_in[4];
    const float* Wv = (const float*)d_in[5];
    const float* bv = (const float*)d_in[6];
    const float* Wo = (const float*)d_in[7];
    const float* bo = (const float*)d_in[8];
    float* out = (float*)d_out;

    const size_t NQ = (size_t)B_ * H_ * S_ * D_;   // 4,194,304 elements
    const size_t NW = (size_t)HID_ * HID_;         // 1,048,576 elements
    unsigned short* p = (unsigned short*)d_ws;
    unsigned short* xh   = p; p += NQ;   // also AOh (x dead after QKV GEMM)
    unsigned short* xl   = p; p += NQ;   // also AOl
    unsigned short* Wt_h[4];
    unsigned short* Wt_l[4];
    for (int i = 0; i < 4; i++) { Wt_h[i] = p; p += NW; Wt_l[i] = p; p += NW; }
    unsigned short* Qhi = p; p += NQ;
    unsigned short* Qlo = p; p += NQ;
    unsigned short* Khi = p; p += NQ;
    unsigned short* Klo = p; p += NQ;
    unsigned short* Vt  = p; p += NQ;
    unsigned short* AOh = xh;
    unsigned short* AOl = xl;

    dim3 blk(256);
    conv_x_k<<<dim3(NQ / 1024), blk, 0, stream>>>(x, xh, xl);
    conv_wT_k<<<dim3(16, 16), blk, 0, stream>>>(Wq, Wt_h[0], Wt_l[0]);
    conv_wT_k<<<dim3(16, 16), blk, 0, stream>>>(Wk, Wt_h[1], Wt_l[1]);
    conv_wT_k<<<dim3(16, 16), blk, 0, stream>>>(Wv, Wt_h[2], Wt_l[2]);
    conv_wT_k<<<dim3(16, 16), blk, 0, stream>>>(Wo, Wt_h[3], Wt_l[3]);

    dim3 gqkv(HID_ / 128, (B_ * S_) / 64, 3);
    gemm_qkv_k<<<gqkv, blk, 0, stream>>>(xh, xl,
        Wt_h[0], Wt_l[0], Wt_h[1], Wt_l[1], Wt_h[2], Wt_l[2],
        bq, bk, bv, Qhi, Qlo, Khi, Klo, Vt);
    attn_topk_k<<<dim3(B_ * H_ * (S_ / QT_)), dim3(1024), 0, stream>>>(
        Qhi, Qlo, Khi, Klo, Vt, AOh, AOl);
    dim3 go(HID_ / 128, (B_ * S_) / 64);
    gemm_o_k<<<go, blk, 0, stream>>>(AOh, AOl, Wt_h[3], Wt_l[3], bo, out);
}